// Round 17
// baseline (273.180 us; speedup 1.0000x reference)
//
#include <hip/hip_runtime.h>
#include <hip/hip_bf16.h>
#include <cstdint>
#include <cstddef>

using u16 = unsigned short;
using u32 = unsigned int;
using f32x4 = __attribute__((ext_vector_type(4))) float;
using bf16x8 = __attribute__((ext_vector_type(8))) short;

#define NB   16        // batch
#define NSEQ 3136      // 56*56
#define NH   8
#define HD   64
#define CDIM 512
#define CQKV 1536

static __device__ __forceinline__ u16 f2bf(float f) {
  u32 u = __builtin_bit_cast(u32, f);
  u = (u + 0x7FFFu + ((u >> 16) & 1u)) >> 16;
  return (u16)u;
}
static __device__ __forceinline__ float bf2f(u16 h) {
  u32 u = ((u32)h) << 16;
  return __builtin_bit_cast(float, u);
}
static __device__ __forceinline__ void async16(const void* g, void* l) {
  __builtin_amdgcn_global_load_lds((const __attribute__((address_space(1))) u32*)g,
                                   (__attribute__((address_space(3))) u32*)l, 16, 0, 0);
}

// ---------------- fused fp32 -> bf16 convert: x, w_qkv, w_proj in one launch ----------------
#define NX4  6422528   // 50176*512/4
#define NW14 196608    // 1536*512/4
#define NW24 65536     // 512*512/4
__global__ __launch_bounds__(256) void cvt3_kernel(const float* __restrict__ x, u16* __restrict__ xb,
                                                   const float* __restrict__ wq, u16* __restrict__ wqb,
                                                   const float* __restrict__ wp, u16* __restrict__ wpb) {
  int i = (int)(blockIdx.x * 256 + threadIdx.x);
  const float* src; u16* dst; int off;
  if (i < NX4)              { src = x;  dst = xb;  off = i; }
  else if (i < NX4 + NW14)  { src = wq; dst = wqb; off = i - NX4; }
  else                      { src = wp; dst = wpb; off = i - NX4 - NW14; }
  f32x4 v = *(const f32x4*)(src + (size_t)off * 4);
  uint2 uu;
  uu.x = (u32)f2bf(v[0]) | ((u32)f2bf(v[1]) << 16);
  uu.y = (u32)f2bf(v[2]) | ((u32)f2bf(v[3]) << 16);
  *(uint2*)(dst + (size_t)off * 4) = uu;
}

// ================= 256x256 8-phase MFMA GEMM (R6/R11 schedule, proven) =================
#define VMW(n) asm volatile("s_waitcnt vmcnt(" #n ")" ::: "memory")

template<bool OUT_FP32>
__global__ __launch_bounds__(512, 2) void gemm256(
    const u16* __restrict__ Ap, const u16* __restrict__ Bp, void* __restrict__ Cp,
    const float* __restrict__ bias, int K, int lda, int ldb, int ldc, int nbn)
{
  __shared__ u16 sm[2][2][2][128 * 64];
  int nwg = (int)gridDim.x;
  int bid = (int)blockIdx.x;
  int wg = (bid & 7) * (nwg >> 3) + (bid >> 3);   // XCD swizzle (nwg % 8 == 0)
  int bm = wg / nbn, bn = wg - bm * nbn;
  int m0 = bm * 256, n0 = bn * 256;
  int t = (int)threadIdx.x;
  int lane = t & 63, w = t >> 6;
  int wm = w >> 2, wn = w & 3;            // 2 x 4 waves
  int lr = lane & 15, lk = (lane >> 4) * 8;

  f32x4 acc[2][2][4][2] = {};             // [Mhalf][Nhalf][mi][ni]
  bf16x8 av[4][2], bv[2][2];              // persistent fragments
  const int KT = K >> 6;

  auto stage = [&](int b, int op, int half, int kt) {
    const u16* P = op ? Bp : Ap;
    int ld = op ? ldb : lda;
    int base0 = op ? n0 : m0;
    int gc = (kt << 6) + ((((t & 7) ^ ((t >> 3) & 7))) << 3);  // inverse-swizzled src
    #pragma unroll
    for (int rd = 0; rd < 2; ++rd) {
      int gr = base0 + half * 128 + rd * 64 + (t >> 3);
      async16(P + (size_t)gr * ld + gc, &sm[b][op][half][rd * 4096 + w * 512]);
    }
  };
  auto LOADA = [&](int b, int h) {
    #pragma unroll
    for (int mi = 0; mi < 4; ++mi)
      #pragma unroll
      for (int kk = 0; kk < 2; ++kk) {
        int r = wm * 64 + mi * 16 + lr;
        int c = kk * 32 + lk;
        av[mi][kk] = *(const bf16x8*)&sm[b][0][h][r * 64 + (c ^ ((r & 7) << 3))];
      }
  };
  auto LOADB = [&](int b, int g) {
    #pragma unroll
    for (int ni = 0; ni < 2; ++ni)
      #pragma unroll
      for (int kk = 0; kk < 2; ++kk) {
        int r = wn * 32 + ni * 16 + lr;
        int c = kk * 32 + lk;
        bv[ni][kk] = *(const bf16x8*)&sm[b][1][g][r * 64 + (c ^ ((r & 7) << 3))];
      }
  };

#define BARSEQ                                                  \
  __builtin_amdgcn_s_barrier();                                 \
  asm volatile("s_waitcnt lgkmcnt(0)" ::: "memory");            \
  __builtin_amdgcn_sched_barrier(0);                            \
  __builtin_amdgcn_s_setprio(1)
#define ENDP                                                    \
  __builtin_amdgcn_s_setprio(0);                                \
  __builtin_amdgcn_s_barrier()
#define MMQ(h_, g_)                                                          \
  _Pragma("unroll")                                                          \
  for (int kk = 0; kk < 2; ++kk) {                                           \
    _Pragma("unroll")                                                        \
    for (int mi = 0; mi < 4; ++mi) {                                         \
      _Pragma("unroll")                                                      \
      for (int ni = 0; ni < 2; ++ni)                                         \
        acc[h_][g_][mi][ni] = __builtin_amdgcn_mfma_f32_16x16x32_bf16(       \
            av[mi][kk], bv[ni][kk], acc[h_][g_][mi][ni], 0, 0, 0);           \
    }                                                                        \
  }

  stage(0, 0, 0, 0); stage(0, 1, 0, 0); stage(0, 0, 1, 0); stage(0, 1, 1, 0);
  VMW(4);
  __builtin_amdgcn_s_barrier();

  for (int kt = 0; kt < KT - 1; ++kt) {
    int bb = kt & 1;
    LOADA(bb, 0); LOADB(bb, 0);
    stage(bb ^ 1, 0, 0, kt + 1);
    VMW(2);
    BARSEQ; MMQ(0, 0); ENDP;
    LOADB(bb, 1);
    stage(bb ^ 1, 1, 0, kt + 1);
    BARSEQ; MMQ(0, 1); ENDP;
    LOADA(bb, 1);
    stage(bb ^ 1, 0, 1, kt + 1);
    BARSEQ; MMQ(1, 1); ENDP;
    LOADB(bb, 0);
    stage(bb ^ 1, 1, 1, kt + 1);
    VMW(4);
    BARSEQ; MMQ(1, 0); ENDP;
  }
  {
    int bb = (KT - 1) & 1;   // peeled last K-tile
    LOADA(bb, 0); LOADB(bb, 0);
    VMW(0);
    BARSEQ; MMQ(0, 0); ENDP;
    LOADB(bb, 1);
    BARSEQ; MMQ(0, 1); ENDP;
    LOADA(bb, 1);
    BARSEQ; MMQ(1, 1); ENDP;
    LOADB(bb, 0);
    BARSEQ; MMQ(1, 0); ENDP;
  }
#undef MMQ
#undef BARSEQ
#undef ENDP

  // ---- epilogue: LDS-staged, bank-swizzled, coalesced stores ----
  if constexpr (!OUT_FP32) {
    __syncthreads();
    u16* cs = (u16*)sm;
    #pragma unroll
    for (int h = 0; h < 2; ++h)
      #pragma unroll
      for (int g = 0; g < 2; ++g)
        #pragma unroll
        for (int mi = 0; mi < 4; ++mi)
          #pragma unroll
          for (int ni = 0; ni < 2; ++ni)
            #pragma unroll
            for (int r = 0; r < 4; ++r) {
              int row = h * 128 + wm * 64 + mi * 16 + (lane >> 4) * 4 + r;
              int col = g * 128 + wn * 32 + ni * 16 + lr;
              cs[row * 256 + (col ^ (((row >> 2) & 7) << 3))] = f2bf(acc[h][g][mi][ni][r]);
            }
    __syncthreads();
    #pragma unroll
    for (int i = 0; i < 16; ++i) {
      int e = (i * 512 + t) * 8;
      int row = e >> 8, col = e & 255;
      uint4 v = *(const uint4*)&cs[row * 256 + (col ^ (((row >> 2) & 7) << 3))];
      *(uint4*)&((u16*)Cp)[(size_t)(m0 + row) * ldc + n0 + col] = v;
    }
  } else {
    float* cf = (float*)sm;   // 128x256 f32 per round
    #pragma unroll
    for (int h = 0; h < 2; ++h) {
      __syncthreads();
      #pragma unroll
      for (int g = 0; g < 2; ++g)
        #pragma unroll
        for (int mi = 0; mi < 4; ++mi)
          #pragma unroll
          for (int ni = 0; ni < 2; ++ni)
            #pragma unroll
            for (int r = 0; r < 4; ++r) {
              int row = wm * 64 + mi * 16 + (lane >> 4) * 4 + r;
              int col = g * 128 + wn * 32 + ni * 16 + lr;
              cf[row * 256 + (col ^ (((row >> 2) & 7) << 3))] = acc[h][g][mi][ni][r];
            }
      __syncthreads();
      #pragma unroll
      for (int i = 0; i < 16; ++i) {
        int e = (i * 512 + t) * 4;
        int row = e >> 8, col = e & 255;
        f32x4 v = *(const f32x4*)&cf[row * 256 + (col ^ (((row >> 2) & 7) << 3))];
        f32x4 b4 = *(const f32x4*)&bias[n0 + col];
        v += b4;
        *(f32x4*)&((float*)Cp)[(size_t)(m0 + h * 128 + row) * ldc + n0 + col] = v;
      }
    }
  }
}

// ======== merged middle kernel: depthwise convs (v -> cvout) ∥ kv partials ========

static __device__ __forceinline__ void kvp_body(int bid, char* smem,
    const u16* __restrict__ qkvb, float* __restrict__ part) {
  int ns = bid & 7, h = (bid >> 3) & 7, b = bid >> 6;
  int t = (int)threadIdx.x;
  int lane = t & 63, w = t >> 6;
  u16* ekT = (u16*)smem;            // [64 dk][64 n] bf16, col = n ^ (c8<<3)
  u16* vT  = (u16*)(smem + 8192);   // [64 dv][64 n] bf16, same swizzle
  int nbase = ns * 392;
  int lr = lane & 15, lg = lane >> 4;
  f32x4 acc[4] = {};
  float sacc = 0.f;

  for (int tile = 0; tile < 7; ++tile) {
    __syncthreads();
    int lim = 392 - tile * 64;
    #pragma unroll
    for (int it = 0; it < 2; ++it) {
      int idx = it * 256 + t;
      int n = idx >> 3, c8 = idx & 7;
      uint4 kq; kq.x = 0u; kq.y = 0u; kq.z = 0u; kq.w = 0u;
      uint4 vq = kq;
      bool ok = (n < lim);
      if (ok) {
        size_t go = (size_t)(b * NSEQ + nbase + tile * 64 + n) * CQKV + h * HD + c8 * 8;
        kq = *(const uint4*)&qkvb[go + CDIM];
        vq = *(const uint4*)&qkvb[go + 2 * CDIM];
      }
      const u16* kp = (const u16*)&kq;
      const u16* vp = (const u16*)&vq;
      int pc = n ^ (c8 << 3);
      #pragma unroll
      for (int j = 0; j < 8; ++j) {
        int d = c8 * 8 + j;
        ekT[d * 64 + pc] = ok ? f2bf(__expf(bf2f(kp[j]))) : (u16)0;
        vT [d * 64 + pc] = vp[j];
      }
    }
    __syncthreads();
    bf16x8 av[2], bv[4][2];
    #pragma unroll
    for (int kk = 0; kk < 2; ++kk) {
      int r = w * 16 + lr;
      int c = kk * 32 + lg * 8;
      av[kk] = *(const bf16x8*)&ekT[r * 64 + (c ^ (((r >> 3) & 7) << 3))];
    }
    #pragma unroll
    for (int ni = 0; ni < 4; ++ni)
      #pragma unroll
      for (int kk = 0; kk < 2; ++kk) {
        int r = ni * 16 + lr;
        int c = kk * 32 + lg * 8;
        bv[ni][kk] = *(const bf16x8*)&vT[r * 64 + (c ^ (((r >> 3) & 7) << 3))];
      }
    #pragma unroll
    for (int kk = 0; kk < 2; ++kk)
      #pragma unroll
      for (int ni = 0; ni < 4; ++ni)
        acc[ni] = __builtin_amdgcn_mfma_f32_16x16x32_bf16(av[kk], bv[ni][kk], acc[ni], 0, 0, 0);
    {
      int r = w * 16 + lr;
      int c0 = lg * 16;
      int sw = (((r >> 3) & 7) << 3);
      bf16x8 s0 = *(const bf16x8*)&ekT[r * 64 + (c0 ^ sw)];
      bf16x8 s1 = *(const bf16x8*)&ekT[r * 64 + ((c0 + 8) ^ sw)];
      float ss = 0.f;
      #pragma unroll
      for (int j = 0; j < 8; ++j) ss += bf2f((u16)s0[j]) + bf2f((u16)s1[j]);
      sacc += ss;
    }
  }
  sacc += __shfl_xor(sacc, 16, 64);
  sacc += __shfl_xor(sacc, 32, 64);
  float* dst = part + (size_t)((ns * 16 + b) * 8 + h) * 4160;
  #pragma unroll
  for (int ni = 0; ni < 4; ++ni)
    #pragma unroll
    for (int r = 0; r < 4; ++r)
      dst[(w * 16 + lg * 4 + r) * 64 + ni * 16 + lr] = acc[ni][r];
  if (lane < 16) dst[4096 + w * 16 + lane] = sacc;
}

// conv: [pix][64ch] staging; 2ch x 1py x OX px per thread, b32 row loads.
// R=1,2: 8x14 output tiles (28/img/head). R=3: 8x7 tiles (56/img/head) to cut
// the halo buffer 35.8->23.3 KB so the kernel max (conv5 27.6 KB) allows 5 blk/CU.
template<int R>
static __device__ __forceinline__ void conv_body(int bid, char* smem,
    const u16* __restrict__ qkvb, u16* __restrict__ cvout,
    const float* __restrict__ wp, const float* __restrict__ bias, int hbase, int nh) {
  constexpr int KS = 2 * R + 1;
  constexpr int OX  = (R == 3) ? 7 : 14;    // output cols per tile
  constexpr int XT  = (R == 3) ? 8 : 4;     // x-tiles per row
  constexpr int TPI = (R == 3) ? 56 : 28;   // tiles per (img, head)
  constexpr int WTY = 8 + 2 * R;
  constexpr int WTX = OX + 2 * R;
  u16* vt = (u16*)smem;
  int hh = bid % nh;
  int tile = (bid / nh) % TPI;
  int b = bid / (nh * TPI);
  int h = hbase + hh;
  int y0 = (tile / XT) * 8, x0 = (tile % XT) * OX;
  int t = (int)threadIdx.x;
  for (int idx = t; idx < WTY * WTX * 8; idx += 256) {
    int pix = idx >> 3, c8 = idx & 7;
    int py = pix / WTX, px = pix - py * WTX;
    int gy = y0 + py - R, gx = x0 + px - R;
    uint4 val; val.x = 0u; val.y = 0u; val.z = 0u; val.w = 0u;
    if (gy >= 0 && gy < 56 && gx >= 0 && gx < 56)
      val = *(const uint4*)&qkvb[(size_t)(b * NSEQ + gy * 56 + gx) * CQKV + 2 * CDIM + h * HD + c8 * 8];
    *(uint4*)&vt[pix * 64 + c8 * 8] = val;
  }
  __syncthreads();
  int d2 = t & 31, py = t >> 5;       // 2 channels, one output row
  int c0 = hh * 64 + d2 * 2;
  float acc0[OX], acc1[OX];
  {
    float bb0 = bias[c0], bb1 = bias[c0 + 1];
    #pragma unroll
    for (int px = 0; px < OX; ++px) { acc0[px] = bb0; acc1[px] = bb1; }
  }
  #pragma unroll
  for (int dy = 0; dy < KS; ++dy) {
    int iy = py + dy;
    float w0[KS], w1[KS];
    #pragma unroll
    for (int dx = 0; dx < KS; ++dx) {
      w0[dx] = wp[c0 * KS * KS + dy * KS + dx];
      w1[dx] = wp[(c0 + 1) * KS * KS + dy * KS + dx];
    }
    float v0[WTX], v1[WTX];
    #pragma unroll
    for (int px = 0; px < WTX; ++px) {
      u32 u = *(const u32*)&vt[(iy * WTX + px) * 64 + d2 * 2];
      v0[px] = __builtin_bit_cast(float, u << 16);
      v1[px] = __builtin_bit_cast(float, u & 0xffff0000u);
    }
    #pragma unroll
    for (int dx = 0; dx < KS; ++dx) {
      #pragma unroll
      for (int px = 0; px < OX; ++px) {
        acc0[px] += w0[dx] * v0[px + dx];
        acc1[px] += w1[dx] * v1[px + dx];
      }
    }
  }
  #pragma unroll
  for (int px = 0; px < OX; ++px) {
    u32 o = (u32)f2bf(acc0[px]) | ((u32)f2bf(acc1[px]) << 16);
    *(u32*)&cvout[(size_t)(b * NSEQ + (y0 + py) * 56 + x0 + px) * CDIM + h * HD + d2 * 2] = o;
  }
}

// 6144 blocks: bid%6==0 -> kvp (1024); others -> convs (4928 bodies + 192 idle)
__global__ __launch_bounds__(256) void mid_kernel(const u16* __restrict__ qkvb,
    u16* __restrict__ cvout, float* __restrict__ part,
    const float* __restrict__ w3, const float* __restrict__ b3,
    const float* __restrict__ w5, const float* __restrict__ b5,
    const float* __restrict__ w7, const float* __restrict__ b7) {
  __shared__ alignas(16) char smem[27648];   // max(conv5 12x18x128, conv7 14x13x128, kvp 16384)
  int bid = (int)blockIdx.x;
  int q6 = bid / 6, r6 = bid - q6 * 6;
  if (r6 == 0) {
    kvp_body(q6, smem, qkvb, part);
  } else {
    int cid = bid - q6 - 1;                  // 0..5119 across non-kvp slots
    if (cid < 896)        conv_body<1>(cid,        smem, qkvb, cvout, w3, b3, 0, 2);
    else if (cid < 2240)  conv_body<2>(cid - 896,  smem, qkvb, cvout, w5, b5, 2, 3);
    else if (cid < 4928)  conv_body<3>(cid - 2240, smem, qkvb, cvout, w7, b7, 5, 3);
    // else: idle tail (192 blocks), retire immediately
  }
}

// ---------------- sum chunks, normalize, write bf16 PRE-SWIZZLED kvT ----------------
__global__ __launch_bounds__(256) void kv_reduce_kernel(const float* __restrict__ part,
                                                        u16* __restrict__ kvbT) {
  int idx = (int)(blockIdx.x * 256 + threadIdx.x);   // vec4 index, < 131072
  int bh = idx >> 10, e4 = idx & 1023;
  int b = bh >> 3, h = bh & 7;
  int dk = e4 >> 4, dv0 = (e4 & 15) * 4;
  float s = 0.f;
  f32x4 o; o[0] = 0.f; o[1] = 0.f; o[2] = 0.f; o[3] = 0.f;
  #pragma unroll
  for (int c = 0; c < 8; ++c) {
    const float* src = part + (size_t)((c * 16 + b) * 8 + h) * 4160;
    o += *(const f32x4*)&src[e4 * 4];
    s += src[4096 + dk];
  }
  float inv = 1.0f / s;
  u16* dst = kvbT + (size_t)bh * 4096;
  #pragma unroll
  for (int j = 0; j < 4; ++j) {
    int dv = dv0 + j;
    dst[dv * 64 + ((((dk >> 3) ^ (dv & 7)) << 3) | (dk & 7))] = f2bf(o[j] * inv);
  }
}

// ---------------- combine (MFMA): out_heads = 0.125*q@kv + q*conv_v, in-place over q ----
__global__ __launch_bounds__(256) void combine_kernel(u16* __restrict__ qkvb,
                                                      const u16* __restrict__ cvin,
                                                      const u16* __restrict__ kvbT) {
  int bid = (int)blockIdx.x;
  int rt = bid % 49;
  int h = (bid / 49) & 7;
  int b = bid / 392;
  int n0 = rt * 64;
  int t = (int)threadIdx.x;
  int lane = t & 63, w = t >> 6;
  __shared__ u16 qs[64 * 72];
  __shared__ u16 cvs[64 * 64];
  __shared__ u16 kvT[64 * 64];

  #pragma unroll
  for (int i = 0; i < 2; ++i) {
    int idx = i * 256 + t;
    int row = idx >> 3, c8 = idx & 7;
    int srccol = (c8 ^ (row & 7)) << 3;
    async16(qkvb + (size_t)(b * NSEQ + n0 + row) * CQKV + h * HD + srccol, &qs[idx * 8]);
    async16(cvin + (size_t)(b * NSEQ + n0 + row) * CDIM + h * HD + srccol, &cvs[idx * 8]);
    async16(kvbT + (size_t)(b * 8 + h) * 4096 + idx * 8, &kvT[idx * 8]);
  }
  VMW(0);
  __syncthreads();

  int lr = lane & 15, lk = (lane >> 4) * 8;
  f32x4 acc[4] = {};
  bf16x8 av[2], bv[4][2];
  #pragma unroll
  for (int kk = 0; kk < 2; ++kk) {
    int r = w * 16 + lr;
    int c = kk * 32 + lk;
    av[kk] = *(const bf16x8*)&qs[r * 64 + (c ^ ((r & 7) << 3))];
  }
  #pragma unroll
  for (int ni = 0; ni < 4; ++ni)
    #pragma unroll
    for (int kk = 0; kk < 2; ++kk) {
      int r = ni * 16 + lr;          // dv
      int c = kk * 32 + lk;          // dk
      bv[ni][kk] = *(const bf16x8*)&kvT[r * 64 + (c ^ ((r & 7) << 3))];
    }
  #pragma unroll
  for (int kk = 0; kk < 2; ++kk)
    #pragma unroll
    for (int ni = 0; ni < 4; ++ni)
      acc[ni] = __builtin_amdgcn_mfma_f32_16x16x32_bf16(av[kk], bv[ni][kk], acc[ni], 0, 0, 0);

  float outv[4][4];
  #pragma unroll
  for (int ni = 0; ni < 4; ++ni)
    #pragma unroll
    for (int r = 0; r < 4; ++r) {
      int nrow = w * 16 + (lane >> 4) * 4 + r;
      int dv = ni * 16 + lr;
      int sw = ((((dv >> 3) ^ (nrow & 7)) << 3) | (dv & 7));
      float qv = bf2f(qs[nrow * 64 + sw]);
      float cv = bf2f(cvs[nrow * 64 + sw]);
      outv[ni][r] = 0.125f * acc[ni][r] + qv * cv;
    }
  __syncthreads();
  #pragma unroll
  for (int ni = 0; ni < 4; ++ni)
    #pragma unroll
    for (int r = 0; r < 4; ++r) {
      int nrow = w * 16 + (lane >> 4) * 4 + r;
      int dv = ni * 16 + lr;
      qs[nrow * 72 + dv] = f2bf(outv[ni][r]);
    }
  __syncthreads();
  {
    int row = t >> 2, c0 = (t & 3) * 16;
    uint4 x0 = *(const uint4*)&qs[row * 72 + c0];
    uint4 x1 = *(const uint4*)&qs[row * 72 + c0 + 8];
    u16* dst = &qkvb[(size_t)(b * NSEQ + n0 + row) * CQKV + h * HD + c0];
    *(uint4*)dst = x0;
    *(uint4*)&dst[8] = x1;
  }
}

// ---------------- launch ----------------
extern "C" void kernel_launch(void* const* d_in, const int* in_sizes, int n_in,
                              void* d_out, int out_size, void* d_ws, size_t ws_size,
                              hipStream_t stream) {
  (void)in_sizes; (void)n_in; (void)out_size; (void)ws_size;
  const float* x      = (const float*)d_in[0];
  // d_in[1]=H, d_in[2]=W (56, hard-coded)
  const float* w_qkv  = (const float*)d_in[3];
  const float* w_proj = (const float*)d_in[4];
  const float* b_proj = (const float*)d_in[5];
  const float* w3 = (const float*)d_in[6];
  const float* b3 = (const float*)d_in[7];
  const float* w5 = (const float*)d_in[8];
  const float* b5 = (const float*)d_in[9];
  const float* w7 = (const float*)d_in[10];
  const float* b7 = (const float*)d_in[11];
  float* out = (float*)d_out;

  char* ws = (char*)d_ws;
  u16* qkvb = (u16*)ws;        ws += (size_t)50176 * 1536 * 2;   // 154.1 MB
  u16* wqb  = (u16*)ws;        ws += (size_t)1536 * 512 * 2;
  u16* wpb  = (u16*)ws;        ws += (size_t)512 * 512 * 2;
  float* kvpart = (float*)ws;  ws += (size_t)1024 * 4160 * 4;    // 17.0 MB
  u16* kvbT = (u16*)ws;        ws += (size_t)16 * 8 * 64 * 64 * 2;  // 1.0 MB
  u16* xb = (u16*)ws;          ws += (size_t)50176 * 512 * 2;    // 51.4 MB (x, then conv_v)

  // one fused convert launch: x, w_qkv, w_proj
  cvt3_kernel<<<26112, 256, 0, stream>>>(x, xb, w_qkv, wqb, w_proj, wpb);
  // qkv = x @ w_qkv^T  (bf16 MFMA, 256^2 8-phase, proven config)
  gemm256<false><<<1176, 512, 0, stream>>>(xb, wqb, qkvb, nullptr,
                                           512, 512, 512, 1536, 6);
  // convs (v -> xb, dead) CONCURRENT with MFMA kv partials; 5 blocks/CU
  mid_kernel<<<6144, 256, 0, stream>>>(qkvb, xb, kvpart, w3, b3, w5, b5, w7, b7);
  // normalize + emit bf16 pre-swizzled kvT
  kv_reduce_kernel<<<512, 256, 0, stream>>>(kvpart, kvbT);
  // out_heads = 0.125*q@kv + q*conv_v  (MFMA, in-place over q, cols 0:512)
  combine_kernel<<<6272, 256, 0, stream>>>(qkvb, xb, kvbT);
  // out = out_heads @ w_proj^T + b_proj  (fp32 out)
  gemm256<true><<<392, 512, 0, stream>>>(qkvb, wpb, out, b_proj,
                                         512, 1536, 512, 512, 2);
}

// Round 18
// 264.459 us; speedup vs baseline: 1.0330x; 1.0330x over previous
//
#include <hip/hip_runtime.h>
#include <hip/hip_bf16.h>
#include <cstdint>
#include <cstddef>

using u16 = unsigned short;
using u32 = unsigned int;
using f32x4 = __attribute__((ext_vector_type(4))) float;
using bf16x8 = __attribute__((ext_vector_type(8))) short;

#define NB   16        // batch
#define NSEQ 3136      // 56*56
#define NH   8
#define HD   64
#define CDIM 512
#define CQKV 1536

static __device__ __forceinline__ u16 f2bf(float f) {
  u32 u = __builtin_bit_cast(u32, f);
  u = (u + 0x7FFFu + ((u >> 16) & 1u)) >> 16;
  return (u16)u;
}
static __device__ __forceinline__ float bf2f(u16 h) {
  u32 u = ((u32)h) << 16;
  return __builtin_bit_cast(float, u);
}
static __device__ __forceinline__ void async16(const void* g, void* l) {
  __builtin_amdgcn_global_load_lds((const __attribute__((address_space(1))) u32*)g,
                                   (__attribute__((address_space(3))) u32*)l, 16, 0, 0);
}

// ---------------- fused fp32 -> bf16 convert: x, w_qkv, w_proj in one launch ----------------
#define NX4  6422528   // 50176*512/4
#define NW14 196608    // 1536*512/4
#define NW24 65536     // 512*512/4
__global__ __launch_bounds__(256) void cvt3_kernel(const float* __restrict__ x, u16* __restrict__ xb,
                                                   const float* __restrict__ wq, u16* __restrict__ wqb,
                                                   const float* __restrict__ wp, u16* __restrict__ wpb) {
  int i = (int)(blockIdx.x * 256 + threadIdx.x);
  const float* src; u16* dst; int off;
  if (i < NX4)              { src = x;  dst = xb;  off = i; }
  else if (i < NX4 + NW14)  { src = wq; dst = wqb; off = i - NX4; }
  else                      { src = wp; dst = wpb; off = i - NX4 - NW14; }
  f32x4 v = *(const f32x4*)(src + (size_t)off * 4);
  uint2 uu;
  uu.x = (u32)f2bf(v[0]) | ((u32)f2bf(v[1]) << 16);
  uu.y = (u32)f2bf(v[2]) | ((u32)f2bf(v[3]) << 16);
  *(uint2*)(dst + (size_t)off * 4) = uu;
}

// ================= 256x256 8-phase MFMA GEMM (R6/R11 schedule, proven) =================
#define VMW(n) asm volatile("s_waitcnt vmcnt(" #n ")" ::: "memory")

template<bool OUT_FP32>
__global__ __launch_bounds__(512, 2) void gemm256(
    const u16* __restrict__ Ap, const u16* __restrict__ Bp, void* __restrict__ Cp,
    const float* __restrict__ bias, int K, int lda, int ldb, int ldc, int nbn)
{
  __shared__ u16 sm[2][2][2][128 * 64];
  int nwg = (int)gridDim.x;
  int bid = (int)blockIdx.x;
  int wg = (bid & 7) * (nwg >> 3) + (bid >> 3);   // XCD swizzle (nwg % 8 == 0)
  int bm = wg / nbn, bn = wg - bm * nbn;
  int m0 = bm * 256, n0 = bn * 256;
  int t = (int)threadIdx.x;
  int lane = t & 63, w = t >> 6;
  int wm = w >> 2, wn = w & 3;            // 2 x 4 waves
  int lr = lane & 15, lk = (lane >> 4) * 8;

  f32x4 acc[2][2][4][2] = {};             // [Mhalf][Nhalf][mi][ni]
  bf16x8 av[4][2], bv[2][2];              // persistent fragments
  const int KT = K >> 6;

  auto stage = [&](int b, int op, int half, int kt) {
    const u16* P = op ? Bp : Ap;
    int ld = op ? ldb : lda;
    int base0 = op ? n0 : m0;
    int gc = (kt << 6) + ((((t & 7) ^ ((t >> 3) & 7))) << 3);  // inverse-swizzled src
    #pragma unroll
    for (int rd = 0; rd < 2; ++rd) {
      int gr = base0 + half * 128 + rd * 64 + (t >> 3);
      async16(P + (size_t)gr * ld + gc, &sm[b][op][half][rd * 4096 + w * 512]);
    }
  };
  auto LOADA = [&](int b, int h) {
    #pragma unroll
    for (int mi = 0; mi < 4; ++mi)
      #pragma unroll
      for (int kk = 0; kk < 2; ++kk) {
        int r = wm * 64 + mi * 16 + lr;
        int c = kk * 32 + lk;
        av[mi][kk] = *(const bf16x8*)&sm[b][0][h][r * 64 + (c ^ ((r & 7) << 3))];
      }
  };
  auto LOADB = [&](int b, int g) {
    #pragma unroll
    for (int ni = 0; ni < 2; ++ni)
      #pragma unroll
      for (int kk = 0; kk < 2; ++kk) {
        int r = wn * 32 + ni * 16 + lr;
        int c = kk * 32 + lk;
        bv[ni][kk] = *(const bf16x8*)&sm[b][1][g][r * 64 + (c ^ ((r & 7) << 3))];
      }
  };

#define BARSEQ                                                  \
  __builtin_amdgcn_s_barrier();                                 \
  asm volatile("s_waitcnt lgkmcnt(0)" ::: "memory");            \
  __builtin_amdgcn_sched_barrier(0);                            \
  __builtin_amdgcn_s_setprio(1)
#define ENDP                                                    \
  __builtin_amdgcn_s_setprio(0);                                \
  __builtin_amdgcn_s_barrier()
#define MMQ(h_, g_)                                                          \
  _Pragma("unroll")                                                          \
  for (int kk = 0; kk < 2; ++kk) {                                           \
    _Pragma("unroll")                                                        \
    for (int mi = 0; mi < 4; ++mi) {                                         \
      _Pragma("unroll")                                                      \
      for (int ni = 0; ni < 2; ++ni)                                         \
        acc[h_][g_][mi][ni] = __builtin_amdgcn_mfma_f32_16x16x32_bf16(       \
            av[mi][kk], bv[ni][kk], acc[h_][g_][mi][ni], 0, 0, 0);           \
    }                                                                        \
  }

  stage(0, 0, 0, 0); stage(0, 1, 0, 0); stage(0, 0, 1, 0); stage(0, 1, 1, 0);
  VMW(4);
  __builtin_amdgcn_s_barrier();

  for (int kt = 0; kt < KT - 1; ++kt) {
    int bb = kt & 1;
    LOADA(bb, 0); LOADB(bb, 0);
    stage(bb ^ 1, 0, 0, kt + 1);
    VMW(2);
    BARSEQ; MMQ(0, 0); ENDP;
    LOADB(bb, 1);
    stage(bb ^ 1, 1, 0, kt + 1);
    BARSEQ; MMQ(0, 1); ENDP;
    LOADA(bb, 1);
    stage(bb ^ 1, 0, 1, kt + 1);
    BARSEQ; MMQ(1, 1); ENDP;
    LOADB(bb, 0);
    stage(bb ^ 1, 1, 1, kt + 1);
    VMW(4);
    BARSEQ; MMQ(1, 0); ENDP;
  }
  {
    int bb = (KT - 1) & 1;   // peeled last K-tile
    LOADA(bb, 0); LOADB(bb, 0);
    VMW(0);
    BARSEQ; MMQ(0, 0); ENDP;
    LOADB(bb, 1);
    BARSEQ; MMQ(0, 1); ENDP;
    LOADA(bb, 1);
    BARSEQ; MMQ(1, 1); ENDP;
    LOADB(bb, 0);
    BARSEQ; MMQ(1, 0); ENDP;
  }
#undef MMQ
#undef BARSEQ
#undef ENDP

  // ---- epilogue: LDS-staged, bank-swizzled, coalesced stores ----
  if constexpr (!OUT_FP32) {
    __syncthreads();
    u16* cs = (u16*)sm;
    #pragma unroll
    for (int h = 0; h < 2; ++h)
      #pragma unroll
      for (int g = 0; g < 2; ++g)
        #pragma unroll
        for (int mi = 0; mi < 4; ++mi)
          #pragma unroll
          for (int ni = 0; ni < 2; ++ni)
            #pragma unroll
            for (int r = 0; r < 4; ++r) {
              int row = h * 128 + wm * 64 + mi * 16 + (lane >> 4) * 4 + r;
              int col = g * 128 + wn * 32 + ni * 16 + lr;
              cs[row * 256 + (col ^ (((row >> 2) & 7) << 3))] = f2bf(acc[h][g][mi][ni][r]);
            }
    __syncthreads();
    #pragma unroll
    for (int i = 0; i < 16; ++i) {
      int e = (i * 512 + t) * 8;
      int row = e >> 8, col = e & 255;
      uint4 v = *(const uint4*)&cs[row * 256 + (col ^ (((row >> 2) & 7) << 3))];
      *(uint4*)&((u16*)Cp)[(size_t)(m0 + row) * ldc + n0 + col] = v;
    }
  } else {
    float* cf = (float*)sm;   // 128x256 f32 per round
    #pragma unroll
    for (int h = 0; h < 2; ++h) {
      __syncthreads();
      #pragma unroll
      for (int g = 0; g < 2; ++g)
        #pragma unroll
        for (int mi = 0; mi < 4; ++mi)
          #pragma unroll
          for (int ni = 0; ni < 2; ++ni)
            #pragma unroll
            for (int r = 0; r < 4; ++r) {
              int row = wm * 64 + mi * 16 + (lane >> 4) * 4 + r;
              int col = g * 128 + wn * 32 + ni * 16 + lr;
              cf[row * 256 + (col ^ (((row >> 2) & 7) << 3))] = acc[h][g][mi][ni][r];
            }
      __syncthreads();
      #pragma unroll
      for (int i = 0; i < 16; ++i) {
        int e = (i * 512 + t) * 4;
        int row = e >> 8, col = e & 255;
        f32x4 v = *(const f32x4*)&cf[row * 256 + (col ^ (((row >> 2) & 7) << 3))];
        f32x4 b4 = *(const f32x4*)&bias[n0 + col];
        v += b4;
        *(f32x4*)&((float*)Cp)[(size_t)(m0 + h * 128 + row) * ldc + n0 + col] = v;
      }
    }
  }
}

// ======== merged middle kernel: depthwise convs (v -> cvout) ∥ kv partials ========

static __device__ __forceinline__ void kvp_body(int bid, char* smem,
    const u16* __restrict__ qkvb, float* __restrict__ part) {
  int ns = bid & 7, h = (bid >> 3) & 7, b = bid >> 6;
  int t = (int)threadIdx.x;
  int lane = t & 63, w = t >> 6;
  u16* ekT = (u16*)smem;            // [64 dk][64 n] bf16, col = n ^ (c8<<3)
  u16* vT  = (u16*)(smem + 8192);   // [64 dv][64 n] bf16, same swizzle
  int nbase = ns * 392;
  int lr = lane & 15, lg = lane >> 4;
  f32x4 acc[4] = {};
  float sacc = 0.f;

  for (int tile = 0; tile < 7; ++tile) {
    __syncthreads();
    int lim = 392 - tile * 64;
    #pragma unroll
    for (int it = 0; it < 2; ++it) {
      int idx = it * 256 + t;
      int n = idx >> 3, c8 = idx & 7;
      uint4 kq; kq.x = 0u; kq.y = 0u; kq.z = 0u; kq.w = 0u;
      uint4 vq = kq;
      bool ok = (n < lim);
      if (ok) {
        size_t go = (size_t)(b * NSEQ + nbase + tile * 64 + n) * CQKV + h * HD + c8 * 8;
        kq = *(const uint4*)&qkvb[go + CDIM];
        vq = *(const uint4*)&qkvb[go + 2 * CDIM];
      }
      const u16* kp = (const u16*)&kq;
      const u16* vp = (const u16*)&vq;
      int pc = n ^ (c8 << 3);
      #pragma unroll
      for (int j = 0; j < 8; ++j) {
        int d = c8 * 8 + j;
        ekT[d * 64 + pc] = ok ? f2bf(__expf(bf2f(kp[j]))) : (u16)0;
        vT [d * 64 + pc] = vp[j];
      }
    }
    __syncthreads();
    bf16x8 av[2], bv[4][2];
    #pragma unroll
    for (int kk = 0; kk < 2; ++kk) {
      int r = w * 16 + lr;
      int c = kk * 32 + lg * 8;
      av[kk] = *(const bf16x8*)&ekT[r * 64 + (c ^ (((r >> 3) & 7) << 3))];
    }
    #pragma unroll
    for (int ni = 0; ni < 4; ++ni)
      #pragma unroll
      for (int kk = 0; kk < 2; ++kk) {
        int r = ni * 16 + lr;
        int c = kk * 32 + lg * 8;
        bv[ni][kk] = *(const bf16x8*)&vT[r * 64 + (c ^ (((r >> 3) & 7) << 3))];
      }
    #pragma unroll
    for (int kk = 0; kk < 2; ++kk)
      #pragma unroll
      for (int ni = 0; ni < 4; ++ni)
        acc[ni] = __builtin_amdgcn_mfma_f32_16x16x32_bf16(av[kk], bv[ni][kk], acc[ni], 0, 0, 0);
    {
      int r = w * 16 + lr;
      int c0 = lg * 16;
      int sw = (((r >> 3) & 7) << 3);
      bf16x8 s0 = *(const bf16x8*)&ekT[r * 64 + (c0 ^ sw)];
      bf16x8 s1 = *(const bf16x8*)&ekT[r * 64 + ((c0 + 8) ^ sw)];
      float ss = 0.f;
      #pragma unroll
      for (int j = 0; j < 8; ++j) ss += bf2f((u16)s0[j]) + bf2f((u16)s1[j]);
      sacc += ss;
    }
  }
  sacc += __shfl_xor(sacc, 16, 64);
  sacc += __shfl_xor(sacc, 32, 64);
  float* dst = part + (size_t)((ns * 16 + b) * 8 + h) * 4160;
  #pragma unroll
  for (int ni = 0; ni < 4; ++ni)
    #pragma unroll
    for (int r = 0; r < 4; ++r)
      dst[(w * 16 + lg * 4 + r) * 64 + ni * 16 + lr] = acc[ni][r];
  if (lane < 16) dst[4096 + w * 16 + lane] = sacc;
}

// conv: [pix][64ch] staging; 2ch x 1py x 14px per thread, b32 row loads (R15/R16 proven)
template<int R>
static __device__ __forceinline__ void conv_body(int bid, char* smem,
    const u16* __restrict__ qkvb, u16* __restrict__ cvout,
    const float* __restrict__ wp, const float* __restrict__ bias, int hbase, int nh) {
  constexpr int KS = 2 * R + 1;
  constexpr int WTY = 8 + 2 * R;
  constexpr int WTX = 14 + 2 * R;
  u16* vt = (u16*)smem;
  int hh = bid % nh;
  int tile = (bid / nh) % 28;
  int b = bid / (nh * 28);
  int h = hbase + hh;
  int y0 = (tile >> 2) * 8, x0 = (tile & 3) * 14;
  int t = (int)threadIdx.x;
  for (int idx = t; idx < WTY * WTX * 8; idx += 256) {
    int pix = idx >> 3, c8 = idx & 7;
    int py = pix / WTX, px = pix - py * WTX;
    int gy = y0 + py - R, gx = x0 + px - R;
    uint4 val; val.x = 0u; val.y = 0u; val.z = 0u; val.w = 0u;
    if (gy >= 0 && gy < 56 && gx >= 0 && gx < 56)
      val = *(const uint4*)&qkvb[(size_t)(b * NSEQ + gy * 56 + gx) * CQKV + 2 * CDIM + h * HD + c8 * 8];
    *(uint4*)&vt[pix * 64 + c8 * 8] = val;
  }
  __syncthreads();
  int d2 = t & 31, py = t >> 5;       // 2 channels, one output row
  int c0 = hh * 64 + d2 * 2;
  float acc0[14], acc1[14];
  {
    float bb0 = bias[c0], bb1 = bias[c0 + 1];
    #pragma unroll
    for (int px = 0; px < 14; ++px) { acc0[px] = bb0; acc1[px] = bb1; }
  }
  #pragma unroll
  for (int dy = 0; dy < KS; ++dy) {
    int iy = py + dy;
    float w0[KS], w1[KS];
    #pragma unroll
    for (int dx = 0; dx < KS; ++dx) {
      w0[dx] = wp[c0 * KS * KS + dy * KS + dx];
      w1[dx] = wp[(c0 + 1) * KS * KS + dy * KS + dx];
    }
    float v0[WTX], v1[WTX];
    #pragma unroll
    for (int px = 0; px < WTX; ++px) {
      u32 u = *(const u32*)&vt[(iy * WTX + px) * 64 + d2 * 2];
      v0[px] = __builtin_bit_cast(float, u << 16);
      v1[px] = __builtin_bit_cast(float, u & 0xffff0000u);
    }
    #pragma unroll
    for (int dx = 0; dx < KS; ++dx) {
      #pragma unroll
      for (int px = 0; px < 14; ++px) {
        acc0[px] += w0[dx] * v0[px + dx];
        acc1[px] += w1[dx] * v1[px + dx];
      }
    }
  }
  #pragma unroll
  for (int px = 0; px < 14; ++px) {
    u32 o = (u32)f2bf(acc0[px]) | ((u32)f2bf(acc1[px]) << 16);
    *(u32*)&cvout[(size_t)(b * NSEQ + (y0 + py) * 56 + x0 + px) * CDIM + h * HD + d2 * 2] = o;
  }
}

// 4608 blocks: bid%9 in {0,4} -> kvp (1024); other 7/9 -> convs (3584)
__global__ __launch_bounds__(256) void mid_kernel(const u16* __restrict__ qkvb,
    u16* __restrict__ cvout, float* __restrict__ part,
    const float* __restrict__ w3, const float* __restrict__ b3,
    const float* __restrict__ w5, const float* __restrict__ b5,
    const float* __restrict__ w7, const float* __restrict__ b7) {
  __shared__ alignas(16) char smem[35840];   // max(conv7 14x20x128, kvp 16384)
  int bid = (int)blockIdx.x;
  int q9 = bid / 9, r9 = bid - q9 * 9;
  if (r9 == 0 || r9 == 4) {
    kvp_body(q9 * 2 + (r9 == 4 ? 1 : 0), smem, qkvb, part);
  } else {
    int s = (r9 < 4) ? (r9 - 1) : (r9 - 2);  // 0..6
    int cid = q9 * 7 + s;                    // 0..3583
    if (cid < 896)        conv_body<1>(cid,        smem, qkvb, cvout, w3, b3, 0, 2);
    else if (cid < 2240)  conv_body<2>(cid - 896,  smem, qkvb, cvout, w5, b5, 2, 3);
    else                  conv_body<3>(cid - 2240, smem, qkvb, cvout, w7, b7, 5, 3);
  }
}

// ---------------- sum chunks, normalize, write bf16 PRE-SWIZZLED kvT ----------------
__global__ __launch_bounds__(256) void kv_reduce_kernel(const float* __restrict__ part,
                                                        u16* __restrict__ kvbT) {
  int idx = (int)(blockIdx.x * 256 + threadIdx.x);   // vec4 index, < 131072
  int bh = idx >> 10, e4 = idx & 1023;
  int b = bh >> 3, h = bh & 7;
  int dk = e4 >> 4, dv0 = (e4 & 15) * 4;
  float s = 0.f;
  f32x4 o; o[0] = 0.f; o[1] = 0.f; o[2] = 0.f; o[3] = 0.f;
  #pragma unroll
  for (int c = 0; c < 8; ++c) {
    const float* src = part + (size_t)((c * 16 + b) * 8 + h) * 4160;
    o += *(const f32x4*)&src[e4 * 4];
    s += src[4096 + dk];
  }
  float inv = 1.0f / s;
  u16* dst = kvbT + (size_t)bh * 4096;
  #pragma unroll
  for (int j = 0; j < 4; ++j) {
    int dv = dv0 + j;
    dst[dv * 64 + ((((dk >> 3) ^ (dv & 7)) << 3) | (dk & 7))] = f2bf(o[j] * inv);
  }
}

// ---------------- combine (MFMA): out_heads = 0.125*q@kv + q*conv_v, in-place over q ----
__global__ __launch_bounds__(256) void combine_kernel(u16* __restrict__ qkvb,
                                                      const u16* __restrict__ cvin,
                                                      const u16* __restrict__ kvbT) {
  int bid = (int)blockIdx.x;
  int rt = bid % 49;
  int h = (bid / 49) & 7;
  int b = bid / 392;
  int n0 = rt * 64;
  int t = (int)threadIdx.x;
  int lane = t & 63, w = t >> 6;
  __shared__ u16 qs[64 * 72];
  __shared__ u16 cvs[64 * 64];
  __shared__ u16 kvT[64 * 64];

  #pragma unroll
  for (int i = 0; i < 2; ++i) {
    int idx = i * 256 + t;
    int row = idx >> 3, c8 = idx & 7;
    int srccol = (c8 ^ (row & 7)) << 3;
    async16(qkvb + (size_t)(b * NSEQ + n0 + row) * CQKV + h * HD + srccol, &qs[idx * 8]);
    async16(cvin + (size_t)(b * NSEQ + n0 + row) * CDIM + h * HD + srccol, &cvs[idx * 8]);
    async16(kvbT + (size_t)(b * 8 + h) * 4096 + idx * 8, &kvT[idx * 8]);
  }
  VMW(0);
  __syncthreads();

  int lr = lane & 15, lk = (lane >> 4) * 8;
  f32x4 acc[4] = {};
  bf16x8 av[2], bv[4][2];
  #pragma unroll
  for (int kk = 0; kk < 2; ++kk) {
    int r = w * 16 + lr;
    int c = kk * 32 + lk;
    av[kk] = *(const bf16x8*)&qs[r * 64 + (c ^ ((r & 7) << 3))];
  }
  #pragma unroll
  for (int ni = 0; ni < 4; ++ni)
    #pragma unroll
    for (int kk = 0; kk < 2; ++kk) {
      int r = ni * 16 + lr;          // dv
      int c = kk * 32 + lk;          // dk
      bv[ni][kk] = *(const bf16x8*)&kvT[r * 64 + (c ^ ((r & 7) << 3))];
    }
  #pragma unroll
  for (int kk = 0; kk < 2; ++kk)
    #pragma unroll
    for (int ni = 0; ni < 4; ++ni)
      acc[ni] = __builtin_amdgcn_mfma_f32_16x16x32_bf16(av[kk], bv[ni][kk], acc[ni], 0, 0, 0);

  float outv[4][4];
  #pragma unroll
  for (int ni = 0; ni < 4; ++ni)
    #pragma unroll
    for (int r = 0; r < 4; ++r) {
      int nrow = w * 16 + (lane >> 4) * 4 + r;
      int dv = ni * 16 + lr;
      int sw = ((((dv >> 3) ^ (nrow & 7)) << 3) | (dv & 7));
      float qv = bf2f(qs[nrow * 64 + sw]);
      float cv = bf2f(cvs[nrow * 64 + sw]);
      outv[ni][r] = 0.125f * acc[ni][r] + qv * cv;
    }
  __syncthreads();
  #pragma unroll
  for (int ni = 0; ni < 4; ++ni)
    #pragma unroll
    for (int r = 0; r < 4; ++r) {
      int nrow = w * 16 + (lane >> 4) * 4 + r;
      int dv = ni * 16 + lr;
      qs[nrow * 72 + dv] = f2bf(outv[ni][r]);
    }
  __syncthreads();
  {
    int row = t >> 2, c0 = (t & 3) * 16;
    uint4 x0 = *(const uint4*)&qs[row * 72 + c0];
    uint4 x1 = *(const uint4*)&qs[row * 72 + c0 + 8];
    u16* dst = &qkvb[(size_t)(b * NSEQ + n0 + row) * CQKV + h * HD + c0];
    *(uint4*)dst = x0;
    *(uint4*)&dst[8] = x1;
  }
}

// ---------------- launch ----------------
extern "C" void kernel_launch(void* const* d_in, const int* in_sizes, int n_in,
                              void* d_out, int out_size, void* d_ws, size_t ws_size,
                              hipStream_t stream) {
  (void)in_sizes; (void)n_in; (void)out_size; (void)ws_size;
  const float* x      = (const float*)d_in[0];
  // d_in[1]=H, d_in[2]=W (56, hard-coded)
  const float* w_qkv  = (const float*)d_in[3];
  const float* w_proj = (const float*)d_in[4];
  const float* b_proj = (const float*)d_in[5];
  const float* w3 = (const float*)d_in[6];
  const float* b3 = (const float*)d_in[7];
  const float* w5 = (const float*)d_in[8];
  const float* b5 = (const float*)d_in[9];
  const float* w7 = (const float*)d_in[10];
  const float* b7 = (const float*)d_in[11];
  float* out = (float*)d_out;

  char* ws = (char*)d_ws;
  u16* qkvb = (u16*)ws;        ws += (size_t)50176 * 1536 * 2;   // 154.1 MB
  u16* wqb  = (u16*)ws;        ws += (size_t)1536 * 512 * 2;
  u16* wpb  = (u16*)ws;        ws += (size_t)512 * 512 * 2;
  float* kvpart = (float*)ws;  ws += (size_t)1024 * 4160 * 4;    // 17.0 MB
  u16* kvbT = (u16*)ws;        ws += (size_t)16 * 8 * 64 * 64 * 2;  // 1.0 MB
  u16* xb = (u16*)ws;          ws += (size_t)50176 * 512 * 2;    // 51.4 MB (x, then conv_v)

  // one fused convert launch: x, w_qkv, w_proj
  cvt3_kernel<<<26112, 256, 0, stream>>>(x, xb, w_qkv, wqb, w_proj, wpb);
  // qkv = x @ w_qkv^T  (bf16 MFMA, 256^2 8-phase, proven config)
  gemm256<false><<<1176, 512, 0, stream>>>(xb, wqb, qkvb, nullptr,
                                           512, 512, 512, 1536, 6);
  // convs (v -> xb, dead) CONCURRENT with MFMA kv partials (R16 proven config)
  mid_kernel<<<4608, 256, 0, stream>>>(qkvb, xb, kvpart, w3, b3, w5, b5, w7, b7);
  // normalize + emit bf16 pre-swizzled kvT
  kv_reduce_kernel<<<512, 256, 0, stream>>>(kvpart, kvbT);
  // out_heads = 0.125*q@kv + q*conv_v  (MFMA, in-place over q, cols 0:512)
  combine_kernel<<<6272, 256, 0, stream>>>(qkvb, xb, kvbT);
  // out = out_heads @ w_proj^T + b_proj  (fp32 out)
  gemm256<true><<<392, 512, 0, stream>>>(qkvb, wpb, out, b_proj,
                                         512, 1536, 512, 512, 2);
}